// Round 1
// baseline (294.478 us; speedup 1.0000x reference)
//
#include <hip/hip_runtime.h>
#include <math.h>

// GCN is linear: out = (1^T M^3 X) W1W2W3/sqrt(N) + bias terms.
// M[d,s] = dinv[d]*dinv[s] per edge s->d, + dinv[i]^2 on the diagonal.
// We compute z_{l+1} = M^T z_l (scalar per node), then one weighted
// reduction over X (the only 51 MB pass), then a tiny 128-wide chain.

#define TPB 256
#define WSUM_BLOCKS 512

__global__ void k_deg(const int* __restrict__ dst, float* __restrict__ deg, int E) {
    int e = blockIdx.x * blockDim.x + threadIdx.x;
    if (e < E) atomicAdd(&deg[dst[e]], 1.0f);
}

// deg (counts) -> dinv in place; z1 self-term (zin == 1): z1[i] = dinv[i]^2
__global__ void k_dinv_z1(float* __restrict__ degdinv, float* __restrict__ z1, int N) {
    int i = blockIdx.x * blockDim.x + threadIdx.x;
    if (i < N) {
        float dv = (float)(1.0 / sqrt((double)degdinv[i] + 1.0));
        degdinv[i] = dv;
        z1[i] = dv * dv;
    }
}

// zout[src] += dinv[src]*dinv[dst]*zin[dst]   (zin == nullptr means zin==1)
__global__ void k_edge(const int* __restrict__ src, const int* __restrict__ dst,
                       const float* __restrict__ dinv, const float* __restrict__ zin,
                       float* __restrict__ zout, int E) {
    int e = blockIdx.x * blockDim.x + threadIdx.x;
    if (e < E) {
        int s = src[e], d = dst[e];
        float zv = zin ? zin[d] : 1.0f;
        atomicAdd(&zout[s], dinv[s] * dinv[d] * zv);
    }
}

// zout[i] = dinv[i]^2 * zin[i]  (self term, plain write — no pre-zero needed)
// and sig += sum(zin)  (block reduce + one atomic per block)
__global__ void k_self_sig(const float* __restrict__ dinv, const float* __restrict__ zin,
                           float* __restrict__ zout, float* __restrict__ sig, int N) {
    __shared__ float red[TPB];
    int i = blockIdx.x * blockDim.x + threadIdx.x;
    float v = 0.0f;
    if (i < N) {
        float dv = dinv[i];
        v = zin[i];
        zout[i] = dv * dv * v;
    }
    red[threadIdx.x] = v;
    __syncthreads();
    for (int s = TPB / 2; s > 0; s >>= 1) {
        if (threadIdx.x < s) red[threadIdx.x] += red[threadIdx.x + s];
        __syncthreads();
    }
    if (threadIdx.x == 0) atomicAdd(sig, red[0]);
}

// partials[b][0:128] = sum over this block's rows of z[r] * X[r][0:128]
__global__ void k_wsum(const float* __restrict__ x, const float* __restrict__ z,
                       float* __restrict__ partials, int N) {
    int tid = threadIdx.x;
    int c4 = (tid & 31) * 4;   // 32 threads cover 128 cols as float4
    int rg = tid >> 5;         // 8 row-groups per 256-thread block
    float4 acc = make_float4(0.f, 0.f, 0.f, 0.f);
    for (int r = blockIdx.x * 8 + rg; r < N; r += gridDim.x * 8) {
        float zv = z[r];
        const float4 xv = *(const float4*)(x + (size_t)r * 128 + c4);
        acc.x += zv * xv.x; acc.y += zv * xv.y;
        acc.z += zv * xv.z; acc.w += zv * xv.w;
    }
    __shared__ float4 red[TPB];
    red[tid] = acc;
    __syncthreads();
    if (tid < 32) {
        float4 a = red[tid];
        #pragma unroll
        for (int g = 1; g < 8; ++g) {
            float4 b = red[tid + 32 * g];
            a.x += b.x; a.y += b.y; a.z += b.z; a.w += b.w;
        }
        float* p = partials + (size_t)blockIdx.x * 128 + c4;
        p[0] = a.x; p[1] = a.y; p[2] = a.z; p[3] = a.w;
    }
}

// Reduce partials -> u0, then u1 = u0 W1 + s2 b1 ; u2 = u1 W2 + s1 b2 ;
// u3 = u2 W3 + N b3 ; out = u3 / sqrt(N).  One block, 512 threads.
__global__ void k_final(const float* __restrict__ partials, int nb,
                        const float* __restrict__ Ws, const float* __restrict__ bs,
                        const float* __restrict__ sig, float* __restrict__ out, int N) {
    __shared__ float uv[128];
    __shared__ float red[512];
    int t = threadIdx.x;
    int j = t & 127, g = t >> 7;
    float acc = 0.0f;
    for (int b = g; b < nb; b += 4) acc += partials[(size_t)b * 128 + j];
    red[t] = acc;
    __syncthreads();
    if (t < 128) uv[t] = red[t] + red[t + 128] + red[t + 256] + red[t + 384];
    __syncthreads();
    float s1 = sig[0], s2 = sig[1];
    for (int l = 0; l < 3; ++l) {
        float a = 0.0f;
        if (t < 128) {
            const float* W = Ws + (size_t)l * 128 * 128;
            #pragma unroll 8
            for (int k = 0; k < 128; ++k) a += uv[k] * W[k * 128 + j];
            float coef = (l == 0) ? s2 : (l == 1) ? s1 : (float)N;
            a += coef * bs[l * 128 + j];
        }
        __syncthreads();
        if (t < 128) uv[t] = a;
        __syncthreads();
    }
    if (t < 128) out[t] = uv[t] * (float)(1.0 / sqrt((double)N));
}

extern "C" void kernel_launch(void* const* d_in, const int* in_sizes, int n_in,
                              void* d_out, int out_size, void* d_ws, size_t ws_size,
                              hipStream_t stream) {
    const int*   ei = (const int*)d_in[0];
    const float* X  = (const float*)d_in[1];
    const float* Ws = (const float*)d_in[2];
    const float* bs = (const float*)d_in[3];
    float* out = (float*)d_out;

    int E = in_sizes[0] / 2;
    int N = in_sizes[1] / 128;
    const int* src = ei;
    const int* dst = ei + E;

    float* ws       = (float*)d_ws;
    float* deg_dinv = ws;               // [N]
    float* sig      = ws + N;           // [2] (+2 pad)
    float* z1       = ws + N + 4;       // [N]
    float* z2       = z1 + N;           // [N]
    float* z3       = z2 + N;           // [N]
    float* partials = z3 + N;           // [WSUM_BLOCKS*128]

    // zero deg + sig only; z1/z2/z3 are fully written by self-term kernels
    hipMemsetAsync(d_ws, 0, (size_t)(N + 4) * sizeof(float), stream);

    int gE = (E + TPB - 1) / TPB;
    int gN = (N + TPB - 1) / TPB;

    k_deg    <<<gE, TPB, 0, stream>>>(dst, deg_dinv, E);
    k_dinv_z1<<<gN, TPB, 0, stream>>>(deg_dinv, z1, N);
    k_edge   <<<gE, TPB, 0, stream>>>(src, dst, deg_dinv, nullptr, z1, E);   // z1 = M^T 1
    k_self_sig<<<gN, TPB, 0, stream>>>(deg_dinv, z1, z2, &sig[0], N);        // sig1 = sum z1
    k_edge   <<<gE, TPB, 0, stream>>>(src, dst, deg_dinv, z1, z2, E);        // z2 = M^T z1
    k_self_sig<<<gN, TPB, 0, stream>>>(deg_dinv, z2, z3, &sig[1], N);        // sig2 = sum z2
    k_edge   <<<gE, TPB, 0, stream>>>(src, dst, deg_dinv, z2, z3, E);        // z3 = M^T z2
    k_wsum   <<<WSUM_BLOCKS, TPB, 0, stream>>>(X, z3, partials, N);          // u0 partials
    k_final  <<<1, 512, 0, stream>>>(partials, WSUM_BLOCKS, Ws, bs, sig, out, N);
}

// Round 2
// 265.506 us; speedup vs baseline: 1.1091x; 1.1091x over previous
//
#include <hip/hip_runtime.h>
#include <math.h>

// GCN is linear: out = ((z3^T X) W1 + s2 b1) W2 + s1 b2) W3 + N b3) / sqrt(N)
// where z1 = M^T 1, z2 = M^T z1, z3 = M^T z2, s1 = sum(z1), s2 = sum(z2),
// M = D^{-1/2}(A+I)D^{-1/2}.  Edge weight w_e = dinv[src]*dinv[dst] is
// computed once (fused into the z1 pass) and reused by the z2/z3 passes.

#define TPB 256
#define WSUM_BLOCKS 512

__global__ void k_deg(const int* __restrict__ dst, float* __restrict__ deg, int E) {
    int i = blockIdx.x * blockDim.x + threadIdx.x;
    int e0 = i * 4;
    if (e0 + 3 < E) {
        int4 d4 = *(const int4*)(dst + e0);
        atomicAdd(&deg[d4.x], 1.0f);
        atomicAdd(&deg[d4.y], 1.0f);
        atomicAdd(&deg[d4.z], 1.0f);
        atomicAdd(&deg[d4.w], 1.0f);
    } else {
        for (int e = e0; e < E; ++e) atomicAdd(&deg[dst[e]], 1.0f);
    }
}

// deg (counts) -> dinv in place; z1 self-term: z1[i] = dinv[i]^2
__global__ void k_dinv_z1(float* __restrict__ degdinv, float* __restrict__ z1, int N) {
    int i = blockIdx.x * blockDim.x + threadIdx.x;
    if (i < N) {
        float dv = (float)(1.0 / sqrt((double)degdinv[i] + 1.0));
        degdinv[i] = dv;
        z1[i] = dv * dv;
    }
}

// Pass 1: w[e] = dinv[src]*dinv[dst]; z1[src] += w[e]
__global__ void k_edge1(const int* __restrict__ src, const int* __restrict__ dst,
                        const float* __restrict__ dinv, float* __restrict__ w,
                        float* __restrict__ z1, int E) {
    int i = blockIdx.x * blockDim.x + threadIdx.x;
    int e0 = i * 4;
    if (e0 + 3 < E) {
        int4 s4 = *(const int4*)(src + e0);
        int4 d4 = *(const int4*)(dst + e0);
        float4 w4;
        w4.x = dinv[s4.x] * dinv[d4.x];
        w4.y = dinv[s4.y] * dinv[d4.y];
        w4.z = dinv[s4.z] * dinv[d4.z];
        w4.w = dinv[s4.w] * dinv[d4.w];
        *(float4*)(w + e0) = w4;
        atomicAdd(&z1[s4.x], w4.x);
        atomicAdd(&z1[s4.y], w4.y);
        atomicAdd(&z1[s4.z], w4.z);
        atomicAdd(&z1[s4.w], w4.w);
    } else {
        for (int e = e0; e < E; ++e) {
            float we = dinv[src[e]] * dinv[dst[e]];
            w[e] = we;
            atomicAdd(&z1[src[e]], we);
        }
    }
}

// Passes 2,3: zout[src] += w[e] * zin[dst]
__global__ void k_edgew(const int* __restrict__ src, const int* __restrict__ dst,
                        const float* __restrict__ w, const float* __restrict__ zin,
                        float* __restrict__ zout, int E) {
    int i = blockIdx.x * blockDim.x + threadIdx.x;
    int e0 = i * 4;
    if (e0 + 3 < E) {
        int4 s4 = *(const int4*)(src + e0);
        int4 d4 = *(const int4*)(dst + e0);
        float4 w4 = *(const float4*)(w + e0);
        atomicAdd(&zout[s4.x], w4.x * zin[d4.x]);
        atomicAdd(&zout[s4.y], w4.y * zin[d4.y]);
        atomicAdd(&zout[s4.z], w4.z * zin[d4.z]);
        atomicAdd(&zout[s4.w], w4.w * zin[d4.w]);
    } else {
        for (int e = e0; e < E; ++e)
            atomicAdd(&zout[src[e]], w[e] * zin[dst[e]]);
    }
}

// zout[i] = dinv[i]^2 * zin[i] (self term, plain write) ; sig += sum(zin)
__global__ void k_self_sig(const float* __restrict__ dinv, const float* __restrict__ zin,
                           float* __restrict__ zout, float* __restrict__ sig, int N) {
    __shared__ float red[TPB];
    int i = blockIdx.x * blockDim.x + threadIdx.x;
    float v = 0.0f;
    if (i < N) {
        float dv = dinv[i];
        v = zin[i];
        zout[i] = dv * dv * v;
    }
    red[threadIdx.x] = v;
    __syncthreads();
    for (int s = TPB / 2; s > 0; s >>= 1) {
        if (threadIdx.x < s) red[threadIdx.x] += red[threadIdx.x + s];
        __syncthreads();
    }
    if (threadIdx.x == 0) atomicAdd(sig, red[0]);
}

// partials[b][0:128] = sum over this block's rows of z[r] * X[r][0:128]
__global__ void k_wsum(const float* __restrict__ x, const float* __restrict__ z,
                       float* __restrict__ partials, int N) {
    int tid = threadIdx.x;
    int c4 = (tid & 31) * 4;
    int rg = tid >> 5;
    float4 acc = make_float4(0.f, 0.f, 0.f, 0.f);
    for (int r = blockIdx.x * 8 + rg; r < N; r += gridDim.x * 8) {
        float zv = z[r];
        const float4 xv = *(const float4*)(x + (size_t)r * 128 + c4);
        acc.x += zv * xv.x; acc.y += zv * xv.y;
        acc.z += zv * xv.z; acc.w += zv * xv.w;
    }
    __shared__ float4 red[TPB];
    red[tid] = acc;
    __syncthreads();
    if (tid < 32) {
        float4 a = red[tid];
        #pragma unroll
        for (int g = 1; g < 8; ++g) {
            float4 b = red[tid + 32 * g];
            a.x += b.x; a.y += b.y; a.z += b.z; a.w += b.w;
        }
        float* p = partials + (size_t)blockIdx.x * 128 + c4;
        p[0] = a.x; p[1] = a.y; p[2] = a.z; p[3] = a.w;
    }
}

// 1024 threads, 16 waves: reduce partials -> u0, then 3-layer chain with
// 8-way split-K per output column (coalesced W reads, LDS tree reduce).
__global__ __launch_bounds__(1024) void k_final(
        const float* __restrict__ partials, int nb,
        const float* __restrict__ Ws, const float* __restrict__ bs,
        const float* __restrict__ sig, float* __restrict__ out, int N) {
    __shared__ float uv[128];
    __shared__ float red[1024];
    int t = threadIdx.x;
    int j = t & 127, g = t >> 7;            // g in [0,8)
    float acc = 0.0f;
    for (int b = g; b < nb; b += 8) acc += partials[(size_t)b * 128 + j];
    red[t] = acc;
    __syncthreads();
    if (t < 128) {
        float s = 0.0f;
        #pragma unroll
        for (int gg = 0; gg < 8; ++gg) s += red[t + 128 * gg];
        uv[t] = s;
    }
    __syncthreads();
    float s1 = sig[0], s2 = sig[1];
    for (int l = 0; l < 3; ++l) {
        const float* W = Ws + (size_t)l * 16384;
        float a = 0.0f;
        #pragma unroll
        for (int kk = 0; kk < 16; ++kk) {
            int k = g * 16 + kk;
            a += uv[k] * W[k * 128 + j];    // coalesced across j, indep loads
        }
        red[t] = a;
        __syncthreads();
        float nv = 0.0f;
        if (t < 128) {
            float s = 0.0f;
            #pragma unroll
            for (int gg = 0; gg < 8; ++gg) s += red[t + 128 * gg];
            float coef = (l == 0) ? s2 : (l == 1) ? s1 : (float)N;
            nv = s + coef * bs[l * 128 + t];
        }
        __syncthreads();
        if (t < 128) uv[t] = nv;
        __syncthreads();
    }
    if (t < 128) out[t] = uv[t] * (float)(1.0 / sqrt((double)N));
}

extern "C" void kernel_launch(void* const* d_in, const int* in_sizes, int n_in,
                              void* d_out, int out_size, void* d_ws, size_t ws_size,
                              hipStream_t stream) {
    const int*   ei = (const int*)d_in[0];
    const float* X  = (const float*)d_in[1];
    const float* Ws = (const float*)d_in[2];
    const float* bs = (const float*)d_in[3];
    float* out = (float*)d_out;

    int E = in_sizes[0] / 2;
    int N = in_sizes[1] / 128;
    const int* src = ei;
    const int* dst = ei + E;

    float* ws       = (float*)d_ws;
    float* deg_dinv = ws;                       // [N]
    float* sig      = ws + N;                   // [2] (+2 pad)
    float* z1       = ws + N + 4;               // [N]
    float* z2       = z1 + N;                   // [N]
    float* z3       = z2 + N;                   // [N]
    float* partials = z3 + N;                   // [WSUM_BLOCKS*128]
    float* w        = partials + WSUM_BLOCKS * 128;  // [E]

    hipMemsetAsync(d_ws, 0, (size_t)(N + 4) * sizeof(float), stream);

    int gE4 = (E / 4 + TPB - 1) / TPB;   // 4 edges per thread
    int gN  = (N + TPB - 1) / TPB;

    k_deg     <<<gE4, TPB, 0, stream>>>(dst, deg_dinv, E);
    k_dinv_z1 <<<gN,  TPB, 0, stream>>>(deg_dinv, z1, N);
    k_edge1   <<<gE4, TPB, 0, stream>>>(src, dst, deg_dinv, w, z1, E);   // w + z1
    k_self_sig<<<gN,  TPB, 0, stream>>>(deg_dinv, z1, z2, &sig[0], N);   // s1, z2 self
    k_edgew   <<<gE4, TPB, 0, stream>>>(src, dst, w, z1, z2, E);         // z2 = M^T z1
    k_self_sig<<<gN,  TPB, 0, stream>>>(deg_dinv, z2, z3, &sig[1], N);   // s2, z3 self
    k_edgew   <<<gE4, TPB, 0, stream>>>(src, dst, w, z2, z3, E);         // z3 = M^T z2
    k_wsum    <<<WSUM_BLOCKS, TPB, 0, stream>>>(X, z3, partials, N);
    k_final   <<<1, 1024, 0, stream>>>(partials, WSUM_BLOCKS, Ws, bs, sig, out, N);
}